// Round 10
// baseline (74.238 us; speedup 1.0000x reference)
//
#include <hip/hip_runtime.h>
#include <math.h>

#define B_ 64
#define NV_ 256
#define N_ 768
#define MAXNNZ 16
#define M_ (B_ * N_)   // 49152 rows

typedef unsigned short us8 __attribute__((ext_vector_type(8)));
typedef unsigned short us4 __attribute__((ext_vector_type(4)));
typedef __bf16 bf16x8 __attribute__((ext_vector_type(8)));
typedef float f32x4 __attribute__((ext_vector_type(4)));

__device__ inline float bf2f(unsigned short u) {
    return __uint_as_float(((unsigned int)u) << 16);
}
__device__ inline unsigned short f2bf(float f) {
    unsigned int u = __float_as_uint(f);
    unsigned int r = u + 0x7fffu + ((u >> 16) & 1u);
    return (unsigned short)(r >> 16);
}
__device__ inline bf16x8 ld_bf8(const unsigned short* p) {
    us8 u = *(const us8*)p;
    return __builtin_bit_cast(bf16x8, u);
}

// ---------------- prep A: degrees (dinv), W->bf16, clamp flags ----------------
// blocks 0..191: wave = one row -> dinv; 192..383: W conv; 384: clamp flags

__global__ __launch_bounds__(256) void k_deg_conv(
    const float* __restrict__ A, const float* __restrict__ W2,
    const float* __restrict__ W3, const int* __restrict__ psel, int np,
    const int* __restrict__ c1, int n1, const int* __restrict__ c2, int n2,
    float* __restrict__ dinv, int* __restrict__ clampf,
    unsigned short* __restrict__ W2b, unsigned short* __restrict__ W3b) {
    int blk = blockIdx.x, tid = threadIdx.x;
    if (blk < 192) {
        int wave = tid >> 6, lane = tid & 63;
        int i = blk * 4 + wave;
        float deg = 0.f;
#pragma unroll
        for (int c0 = 0; c0 < N_; c0 += 64) deg += A[(size_t)i * N_ + c0 + lane];
#pragma unroll
        for (int o = 32; o > 0; o >>= 1) deg += __shfl_xor(deg, o);
        if (lane == 0) dinv[i] = (deg == 0.f) ? 0.f : 1.0f / sqrtf(deg);
    } else if (blk < 384) {
        int idx = (blk - 192) * 256 + tid;
        if (idx < 128 * 256) W2b[idx] = f2bf(W2[idx]);
        else W3b[idx - 128 * 256] = f2bf(W3[idx - 128 * 256]);
    } else {
        clampf[tid] = 0;
        clampf[tid + 256] = 0;
        clampf[tid + 512] = 0;
        __syncthreads();
        if (tid < np) clampf[psel[tid]] = 1;
        else if (tid - np < n1) clampf[NV_ + c1[tid - np]] = 1;
        else if (tid - np - n1 < n2) clampf[2 * NV_ + c2[tid - np - n1]] = 1;
    }
}

// ---------------- prep B: ballot-compacted sparse A_norm (round-4 structure) ----------------

__global__ __launch_bounds__(256) void k_sparse(const float* __restrict__ A,
                                                const float* __restrict__ dinv,
                                                int* __restrict__ cols,
                                                float* __restrict__ vals,
                                                int* __restrict__ nnzArr,
                                                float* __restrict__ rowsum) {
    int wave = threadIdx.x >> 6, lane = threadIdx.x & 63;
    int i = blockIdx.x * 4 + wave;
    float di = dinv[i];
    int cnt = 0;
    float rs = 0.f;
#pragma unroll
    for (int c0 = 0; c0 < N_; c0 += 64) {
        int c = c0 + lane;
        float a = A[(size_t)i * N_ + c];
        unsigned long long m = __ballot(a != 0.f);
        if (a != 0.f) {
            float v = a * di * dinv[c];
            int pos = cnt + __popcll(m & ((1ull << lane) - 1ull));
            if (pos < MAXNNZ) {
                cols[i * MAXNNZ + pos] = c;
                vals[i * MAXNNZ + pos] = v;
            }
            rs += v;
        }
        cnt += (int)__popcll(m);
    }
#pragma unroll
    for (int o = 32; o > 0; o >>= 1) rs += __shfl_xor(rs, o);
    if (lane == 0) {
        nnzArr[i] = cnt;
        rowsum[i] = rs;
    }
}

// ---- fused layers 1+2: agg(F=6) -> 6->256 linear+relu (registers) -> MFMA 256->128 ----
// XCD swizzle: bijection, 768 = 8 x 96; same mapping in layer3s -> T2 L2-local per XCD

__global__ __launch_bounds__(256) void k_layer12(
    const float* __restrict__ x, const float* __restrict__ inputs,
    const int* __restrict__ cols, const float* __restrict__ vals,
    const int* __restrict__ nnzArr, const int* __restrict__ clampf,
    const float* __restrict__ rowsum, const float* __restrict__ W1,
    const float* __restrict__ b1, const unsigned short* __restrict__ W2b,
    const float* __restrict__ b2, unsigned short* __restrict__ T2) {
    __shared__ float Xs[64][6];
    __shared__ float W1T[6][256];
    __shared__ float b1s[256];

    int tid = threadIdx.x;
    int blk = ((blockIdx.x & 7) * 96) + (blockIdx.x >> 3);  // XCD swizzle
    int i0 = (blk % 12) * 64;
    int base = (blk / 12) * N_;
    int wave = tid >> 6, lane = tid & 63;
    int lrow = lane & 15, kgrp = lane >> 4;

    for (int t = tid; t < 1536; t += 256) {
        int k = t >> 8, c = t & 255;
        W1T[k][c] = W1[c * 6 + k];
    }
    b1s[tid] = b1[tid];

    for (int t = lane; t < 96; t += 64) {
        int f = t % 6, ro = t / 6;
        int i = i0 + wave * 16 + ro;
        int n = nnzArr[i];
        if (n > MAXNNZ) n = MAXNNZ;
        float s = 0.f;
        for (int k = 0; k < n; ++k) {
            int c = cols[i * MAXNNZ + k];
            float val = (f < 3 && clampf[c]) ? inputs[(size_t)(base + c) * 3 + f]
                                             : x[(size_t)(base + c) * 6 + f];
            s += vals[i * MAXNNZ + k] * val;
        }
        Xs[wave * 16 + ro][f] = s;
    }
    __syncthreads();

    int i = i0 + wave * 16 + lrow;
    size_t g = (size_t)(base + i);
    float rs = rowsum[i];
    float xa[6];
#pragma unroll
    for (int k = 0; k < 6; ++k) xa[k] = Xs[wave * 16 + lrow][k];

    f32x4 acc[8];
#pragma unroll
    for (int j = 0; j < 8; ++j) acc[j] = (f32x4){0.f, 0.f, 0.f, 0.f};

#pragma unroll
    for (int s = 0; s < 8; ++s) {
        int c0 = s * 32 + kgrp * 8;
        float h[8];
        f32x4 bv0 = *(const f32x4*)&b1s[c0];
        f32x4 bv1 = *(const f32x4*)&b1s[c0 + 4];
#pragma unroll
        for (int e = 0; e < 4; ++e) {
            h[e] = rs * bv0[e];
            h[4 + e] = rs * bv1[e];
        }
#pragma unroll
        for (int k = 0; k < 6; ++k) {
            f32x4 w0 = *(const f32x4*)&W1T[k][c0];
            f32x4 w1 = *(const f32x4*)&W1T[k][c0 + 4];
#pragma unroll
            for (int e = 0; e < 4; ++e) {
                h[e] += xa[k] * w0[e];
                h[4 + e] += xa[k] * w1[e];
            }
        }
        us8 o;
#pragma unroll
        for (int e = 0; e < 8; ++e) o[e] = f2bf(fmaxf(h[e], 0.f));
        bf16x8 af = __builtin_bit_cast(bf16x8, o);
#pragma unroll
        for (int j = 0; j < 8; ++j) {
            bf16x8 w = ld_bf8(W2b + (size_t)(j * 16 + lrow) * 256 + c0);
            acc[j] = __builtin_amdgcn_mfma_f32_16x16x32_bf16(w, af, acc[j], 0, 0, 0);
        }
    }

#pragma unroll
    for (int j = 0; j < 8; ++j) {
        f32x4 bv = *(const f32x4*)&b2[j * 16 + kgrp * 4];
        us4 o;
#pragma unroll
        for (int e = 0; e < 4; ++e) o[e] = f2bf(acc[j][e] + bv[e]);
        *(us4*)(T2 + g * 128 + j * 16 + kgrp * 4) = o;
    }
}

// ---- fused layer 3 + W4-dot: relu(agg(T2)) -> MFMA 128->128 -> S = T3row @ W4^T ----

__global__ __launch_bounds__(256) void k_layer3s(
    const unsigned short* __restrict__ T2, const int* __restrict__ cols,
    const float* __restrict__ vals, const int* __restrict__ nnzArr,
    const unsigned short* __restrict__ W3b, const float* __restrict__ b3,
    const float* __restrict__ W4, float* __restrict__ S) {
    __shared__ float W4s[128 * 3];

    int tid = threadIdx.x;
    int blk = ((blockIdx.x & 7) * 96) + (blockIdx.x >> 3);  // XCD swizzle
    int i0 = (blk % 12) * 64;
    int base = (blk / 12) * N_;
    int wave = tid >> 6, lane = tid & 63;
    int lrow = lane & 15, kgrp = lane >> 4;

    for (int t = tid; t < 384; t += 256) {
        int d = t % 3, nfeat = t / 3;
        W4s[t] = W4[d * 128 + nfeat];
    }
    __syncthreads();

    int i = i0 + wave * 16 + lrow;
    size_t g = (size_t)(base + i);
    int n = nnzArr[i];
    if (n > MAXNNZ) n = MAXNNZ;

    float fa[4][8];
#pragma unroll
    for (int s = 0; s < 4; ++s)
#pragma unroll
        for (int e = 0; e < 8; ++e) fa[s][e] = 0.f;

    for (int k = 0; k < n; ++k) {
        int c = cols[i * MAXNNZ + k];
        float v = vals[i * MAXNNZ + k];
        const unsigned short* p = T2 + (size_t)(base + c) * 128 + kgrp * 8;
#pragma unroll
        for (int s = 0; s < 4; ++s) {
            us8 z = *(const us8*)(p + s * 32);
#pragma unroll
            for (int e = 0; e < 8; ++e) fa[s][e] += v * bf2f(z[e]);
        }
    }

    bf16x8 af[4];
#pragma unroll
    for (int s = 0; s < 4; ++s) {
        us8 o;
#pragma unroll
        for (int e = 0; e < 8; ++e) o[e] = f2bf(fmaxf(fa[s][e], 0.f));
        af[s] = __builtin_bit_cast(bf16x8, o);
    }

    f32x4 acc[8];
#pragma unroll
    for (int j = 0; j < 8; ++j) acc[j] = (f32x4){0.f, 0.f, 0.f, 0.f};
#pragma unroll
    for (int s = 0; s < 4; ++s) {
#pragma unroll
        for (int j = 0; j < 8; ++j) {
            bf16x8 w = ld_bf8(W3b + (size_t)(j * 16 + lrow) * 128 + s * 32 + kgrp * 8);
            acc[j] = __builtin_amdgcn_mfma_f32_16x16x32_bf16(w, af[s], acc[j], 0, 0, 0);
        }
    }

    float s0 = 0.f, s1 = 0.f, s2 = 0.f;
#pragma unroll
    for (int j = 0; j < 8; ++j) {
        f32x4 bv = *(const f32x4*)&b3[j * 16 + kgrp * 4];
#pragma unroll
        for (int e = 0; e < 4; ++e) {
            float tv = acc[j][e] + bv[e];
            int nfeat = j * 16 + kgrp * 4 + e;
            s0 += tv * W4s[nfeat * 3 + 0];
            s1 += tv * W4s[nfeat * 3 + 1];
            s2 += tv * W4s[nfeat * 3 + 2];
        }
    }
    s0 += __shfl_xor(s0, 16); s0 += __shfl_xor(s0, 32);
    s1 += __shfl_xor(s1, 16); s1 += __shfl_xor(s1, 32);
    s2 += __shfl_xor(s2, 16); s2 += __shfl_xor(s2, 32);
    if (kgrp == 0) {
        S[g * 3 + 0] = s0;
        S[g * 3 + 1] = s1;
        S[g * 3 + 2] = s2;
    }
}

// ---- final: out = A*(A*S) + rowsum*b4 (two-hop), with output clamp ----

__global__ __launch_bounds__(256) void k_out2(const float* __restrict__ S,
                                              const float* __restrict__ inputs,
                                              const int* __restrict__ cols,
                                              const float* __restrict__ vals,
                                              const int* __restrict__ nnzArr,
                                              const float* __restrict__ rowsum,
                                              const float* __restrict__ b4,
                                              const int* __restrict__ clampf,
                                              float* __restrict__ out) {
    int idx = blockIdx.x * 256 + threadIdx.x;
    if (idx >= M_ * 3) return;
    int f = idx % 3;
    int r = idx / 3;
    int i = r % N_;
    int base = r - i;
    if (clampf[i]) {
        out[idx] = inputs[(size_t)r * 3 + f];
        return;
    }
    int n = nnzArr[i];
    if (n > MAXNNZ) n = MAXNNZ;
    float s = rowsum[i] * b4[f];
    for (int k = 0; k < n; ++k) {
        int c = cols[i * MAXNNZ + k];
        int nc = nnzArr[c];
        if (nc > MAXNNZ) nc = MAXNNZ;
        float u = 0.f;
        for (int p = 0; p < nc; ++p) {
            int j = cols[c * MAXNNZ + p];
            u += vals[c * MAXNNZ + p] * S[(size_t)(base + j) * 3 + f];
        }
        s += vals[i * MAXNNZ + k] * u;
    }
    out[idx] = s;
}

// ---------------- launch ----------------

extern "C" void kernel_launch(void* const* d_in, const int* in_sizes, int n_in,
                              void* d_out, int out_size, void* d_ws, size_t ws_size,
                              hipStream_t stream) {
    const float* x      = (const float*)d_in[0];
    const float* inputs = (const float*)d_in[1];
    const float* A      = (const float*)d_in[2];
    const float* W1     = (const float*)d_in[3];
    const float* b1     = (const float*)d_in[4];
    const float* W2     = (const float*)d_in[5];
    const float* b2     = (const float*)d_in[6];
    const float* W3     = (const float*)d_in[7];
    const float* b3     = (const float*)d_in[8];
    const float* W4     = (const float*)d_in[9];
    const float* b4     = (const float*)d_in[10];
    const int* psel     = (const int*)d_in[11];
    const int* c1sel    = (const int*)d_in[12];
    const int* c2sel    = (const int*)d_in[13];
    int np = in_sizes[11], n1 = in_sizes[12], n2 = in_sizes[13];
    float* out = (float*)d_out;

    char* ws = (char*)d_ws;
    float* dinv            = (float*)(ws + 0);
    float* rowsum          = (float*)(ws + 3072);
    int*   nnzA            = (int*)(ws + 6144);
    int*   clampf          = (int*)(ws + 9216);
    int*   cols            = (int*)(ws + 12288);
    float* vals            = (float*)(ws + 61440);
    unsigned short* W2b    = (unsigned short*)(ws + 110592);
    unsigned short* W3b    = (unsigned short*)(ws + 176128);
    float* S               = (float*)(ws + 417792);
    unsigned short* T2     = (unsigned short*)(ws + 27144192);

    k_deg_conv<<<385, 256, 0, stream>>>(A, W2, W3, psel, np, c1sel, n1, c2sel, n2,
                                        dinv, clampf, W2b, W3b);
    k_sparse<<<192, 256, 0, stream>>>(A, dinv, cols, vals, nnzA, rowsum);

    k_layer12<<<M_ / 64, 256, 0, stream>>>(x, inputs, cols, vals, nnzA, clampf, rowsum,
                                           W1, b1, W2b, b2, T2);
    k_layer3s<<<M_ / 64, 256, 0, stream>>>(T2, cols, vals, nnzA, W3b, b3, W4, S);
    k_out2<<<(M_ * 3 + 255) / 256, 256, 0, stream>>>(S, inputs, cols, vals, nnzA,
                                                     rowsum, b4, clampf, out);
}